// Round 1
// baseline (573.556 us; speedup 1.0000x reference)
//
#include <hip/hip_runtime.h>
#include <cstddef>

// Problem constants (fixed by the reference)
#define F       1024      // feature dim
#define NB      128       // batch (scan steps)
#define KK      4096      // RATE*F = GEMM K
#define KSPLIT  8
#define KCHUNK  512       // KK / KSPLIT
#define KT      32        // k-tile staged in LDS
#define BT      16        // b-tile per block
#define OT      256       // o-tile per block

typedef float f4 __attribute__((ext_vector_type(4)));
typedef float f2 __attribute__((ext_vector_type(2)));

// comp[b,o] = sum_k A[b,k] * Kflat[k,o]   (bias added in reduce)
// A = memory + 512*F viewed as (128 x 4096) row-major (rows are contiguous:
//     memory[512+4b+w][i] flattens to A[b][w*1024+i])
// grid: x = o-tiles (4), y = b-tiles (8), z = ksplit (8)  -> 256 blocks
__global__ __launch_bounds__(256) void gemm_partial(
    const float* __restrict__ mem, const float* __restrict__ kern,
    float* __restrict__ partial)
{
  const int ot = blockIdx.x, bt = blockIdx.y, ks = blockIdx.z;
  const int t  = threadIdx.x;
  const int tx = t & 63;        // 64 o-groups of 4 cols
  const int ty = t >> 6;        // 4 b-groups of 4 rows
  __shared__ float At[KT][BT];  // A tile, transposed [k][b]
  __shared__ float Bt[KT][OT];  // kernel tile [k][o]

  f4 acc[4] = {{0,0,0,0},{0,0,0,0},{0,0,0,0},{0,0,0,0}};
  const float* Ab = mem + 512 * F;

  for (int kc = 0; kc < KCHUNK; kc += KT) {
    const int k0 = ks * KCHUNK + kc;
    // stage A: 16 rows x 32 k, transposed into LDS
    {
      const int b_l = t >> 4;          // 0..15
      const int k_l = (t & 15) * 2;    // 0..30 (even)
      f2 v = *(const f2*)(Ab + (size_t)(bt * BT + b_l) * KK + k0 + k_l);
      At[k_l][b_l]     = v.x;
      At[k_l + 1][b_l] = v.y;
    }
    // stage B: 32 k-rows x 256 cols = 2048 float4, 8 per thread (coalesced)
#pragma unroll
    for (int i = 0; i < 8; ++i) {
      const int fid = t + i * 256;
      const int r = fid >> 6, c4 = fid & 63;
      *(f4*)&Bt[r][c4 * 4] =
          *(const f4*)(kern + (size_t)(k0 + r) * F + ot * OT + c4 * 4);
    }
    __syncthreads();
#pragma unroll
    for (int k = 0; k < KT; ++k) {
      // A read: all 64 lanes of a wave share ty -> broadcast (conflict-free)
      f4 a  = *(const f4*)&At[k][ty * 4];
      // B read: 64 consecutive float4 across the wave -> full-rate
      f4 bv = *(const f4*)&Bt[k][tx * 4];
      acc[0] += a.x * bv;
      acc[1] += a.y * bv;
      acc[2] += a.z * bv;
      acc[3] += a.w * bv;
    }
    __syncthreads();
  }
  float* p = partial + ((size_t)ks * NB + bt * BT + ty * 4) * F + ot * OT + tx * 4;
#pragma unroll
  for (int i = 0; i < 4; ++i) *(f4*)(p + (size_t)i * F) = acc[i];
}

// comp[idx] = bias[o] + sum_ks partial[ks][idx]
__global__ __launch_bounds__(256) void reduce_comp(
    const float* __restrict__ partial, const float* __restrict__ bias,
    float* __restrict__ comp)
{
  const int idx = blockIdx.x * 256 + threadIdx.x;   // 0..131071
  float s = bias[idx & (F - 1)];
#pragma unroll
  for (int ks = 0; ks < KSPLIT; ++ks) s += partial[(size_t)ks * NB * F + idx];
  comp[idx] = s;
}

// Pure gather: out[b,row] is one source row of 1024 floats.
// 4 rows per block, 256 threads (1 float4 each per row). NT stores keep the
// ~6.5 MiB of hot sources (memory/inputs/comp) resident in L2.
__global__ __launch_bounds__(256) void writer(
    const float* __restrict__ inputs, const float* __restrict__ mem,
    const float* __restrict__ comp, float* __restrict__ out)
{
  const int t = threadIdx.x;
  const int base = blockIdx.x * 4;
#pragma unroll
  for (int r = 0; r < 4; ++r) {
    const int gid = base + r;
    const int b = gid >> 10, row = gid & 1023;
    const float* src;
    if (row < 512) {
      const int lim1 = 511 - b;                     // original conv rows kept
      src = (row < lim1) ? (mem + (size_t)(b + 1 + row) * F)
                         : (comp + (size_t)(row - lim1) * F);
    } else {
      const int r2 = row - 512;
      const int c2 = 508 - 4 * b;                   // original short rows kept
      src = (r2 < c2) ? (mem + (size_t)(516 + 4 * b + r2) * F)
                      : (inputs + (size_t)(r2 - c2) * F);
    }
    const f4 v = *(const f4*)(src + t * 4);
    __builtin_nontemporal_store(v, (f4*)(out + (size_t)gid * F + t * 4));
  }
}

extern "C" void kernel_launch(void* const* d_in, const int* in_sizes, int n_in,
                              void* d_out, int out_size, void* d_ws, size_t ws_size,
                              hipStream_t stream) {
  const float* inputs = (const float*)d_in[0];   // (128,4,1024)
  const float* memory = (const float*)d_in[1];   // (1024,1024)
  const float* kern   = (const float*)d_in[2];   // (4,1024,1024)
  const float* bias   = (const float*)d_in[3];   // (1024,)
  float* out = (float*)d_out;                    // (128,1024,1024)

  float* partial = (float*)d_ws;                 // KSPLIT*128*1024 floats = 4 MiB
  float* comp    = partial + (size_t)KSPLIT * NB * F;  // 128*1024 floats

  gemm_partial<<<dim3(4, 8, 8), 256, 0, stream>>>(memory, kern, partial);
  reduce_comp<<<dim3(512), 256, 0, stream>>>(partial, bias, comp);
  writer<<<dim3(32768), 256, 0, stream>>>(inputs, memory, comp, out);
}